// Round 12
// baseline (45.737 us; speedup 1.0000x reference)
//
#include <hip/hip_runtime.h>

// GeometricAttention: B=4, N=256, FDIM=256, REL=16, H=8, D=32
//   K[b,i,j] = Kn[b,j] + rel[b,i,j] @ Wk_r          (Kn = nf@Wk_f + bk)
//   scores   = Q.Kn^T + Qr.rel^T                     (Qr = per-head Q @ Wk_r^T)
//   sum_j attn*V = attn@Vn + (attn@rel)@Wv_r         (Vn = nf@Wv_f + bv)
// Round 12: r11 MFMA core, QI 4->2: 512 attn blocks = 2 blocks/CU (16 waves/CU,
// double the latency hiding); LDS 59->30 KB. k_proj reads nf fp32 directly
// (in-register bf16 pack) so k_prep is W-transposes only.

#define BB 4
#define NN 256
#define FD 256
#define RL 16
#define NH 8
#define HD 32
#define QI 2

typedef __attribute__((ext_vector_type(8))) short bf16x8;
typedef __attribute__((ext_vector_type(4))) float f32x4;

// ws layout (float offsets)
#define OFF_QB   0                          // ushort Qb[b][i][f]  (scaled)
#define OFF_KNA  131072                     // ushort Kn[b][j][f]
#define OFF_VNT  262144                     // ushort VnT[b][f][j]
#define OFF_WT   393216                     // ushort WT[4][c][k]: Wq,Wk_f,Wv_f,Wo

static __device__ __forceinline__ unsigned short f2bf(float x) {
  unsigned int u = __float_as_uint(x);
  unsigned int r = (u + 0x7fffu + ((u >> 16) & 1u)) >> 16;   // RNE
  return (unsigned short)r;
}
static __device__ __forceinline__ float bf2f(unsigned short h) {
  return __uint_as_float(((unsigned int)h) << 16);
}

// ---------------- Kernel 0: W transposes -> WT[c][k] bf16
__global__ __launch_bounds__(256) void k_prep(
    const float* __restrict__ Wq, const float* __restrict__ Wk,
    const float* __restrict__ Wv, const float* __restrict__ Wo,
    float* __restrict__ ws) {
  const int tid = threadIdx.x;
  const int sel = blockIdx.y;          // 0..3: Wq/Wk_f/Wv_f/Wo
  const float* W = (sel == 0) ? Wq : (sel == 1) ? Wk : (sel == 2) ? Wv : Wo;
  unsigned short* WT = (unsigned short*)(ws + OFF_WT) + sel * FD * FD;
  __shared__ unsigned short t[64][72];
  const int tx = blockIdx.x & 3, ty = blockIdx.x >> 2;   // 64x64 tile
  const int cx = tid & 63, r0 = tid >> 6;
  #pragma unroll
  for (int rr = r0; rr < 64; rr += 4)
    t[rr][cx] = f2bf(W[(ty * 64 + rr) * FD + tx * 64 + cx]);
  __syncthreads();
  #pragma unroll
  for (int rr = r0; rr < 64; rr += 4)
    WT[(tx * 64 + rr) * FD + ty * 64 + cx] = t[cx][rr];   // WT[c][k] = W[k][c]
}

// ---------------- Kernel 1: MFMA projections -> Qb / Kn / VnT (all bf16)
__global__ __launch_bounds__(256) void k_proj(
    const float* __restrict__ nf,
    const float* __restrict__ bq, const float* __restrict__ bk,
    const float* __restrict__ bv, float* __restrict__ ws) {
  const int mat = blockIdx.y >> 2;                 // 0=Qb, 1=Kn, 2=VnT
  const int c0 = (blockIdx.y & 3) * 64;
  const int m0 = blockIdx.x * 64 + (threadIdx.x >> 6) * 16;
  const int l = threadIdx.x & 63;
  const unsigned short* WT = (const unsigned short*)(ws + OFF_WT) + mat * FD * FD;
  const int ar = l & 15, kg = l >> 4;
  f32x4 acc[4];
  #pragma unroll
  for (int nt = 0; nt < 4; ++nt) acc[nt] = (f32x4){0.f, 0.f, 0.f, 0.f};
  #pragma unroll
  for (int ks = 0; ks < 8; ++ks) {
    const float* nfp = nf + (m0 + ar) * FD + ks * 32 + kg * 8;
    float4 x0 = *(const float4*)nfp;
    float4 x1 = *(const float4*)(nfp + 4);
    bf16x8 a;
    a[0] = (short)f2bf(x0.x); a[1] = (short)f2bf(x0.y);
    a[2] = (short)f2bf(x0.z); a[3] = (short)f2bf(x0.w);
    a[4] = (short)f2bf(x1.x); a[5] = (short)f2bf(x1.y);
    a[6] = (short)f2bf(x1.z); a[7] = (short)f2bf(x1.w);
    #pragma unroll
    for (int nt = 0; nt < 4; ++nt) {
      bf16x8 b = *(const bf16x8*)(WT + (c0 + nt * 16 + ar) * FD + ks * 32 + kg * 8);
      acc[nt] = __builtin_amdgcn_mfma_f32_16x16x32_bf16(a, b, acc[nt], 0, 0, 0);
    }
  }
  if (mat == 0) {
    const float scale = 0.17677669529663687f;      // 1/sqrt(32)
    unsigned short* Qb = (unsigned short*)(ws + OFF_QB);
    #pragma unroll
    for (int nt = 0; nt < 4; ++nt) {
      const int cc = c0 + nt * 16 + ar;
      const float bb = bq[cc];
      #pragma unroll
      for (int i = 0; i < 4; ++i)
        Qb[(m0 + kg * 4 + i) * FD + cc] = f2bf((acc[nt][i] + bb) * scale);
    }
  } else if (mat == 1) {
    unsigned short* Kn = (unsigned short*)(ws + OFF_KNA);
    #pragma unroll
    for (int nt = 0; nt < 4; ++nt) {
      const int cc = c0 + nt * 16 + ar;
      const float bb = bk[cc];
      #pragma unroll
      for (int i = 0; i < 4; ++i)
        Kn[(m0 + kg * 4 + i) * FD + cc] = f2bf(acc[nt][i] + bb);
    }
  } else {
    unsigned short* VnT = (unsigned short*)(ws + OFF_VNT);
    const int b2 = m0 >> 8, j0 = (m0 & 255) + kg * 4;
    #pragma unroll
    for (int nt = 0; nt < 4; ++nt) {
      const int cc = c0 + nt * 16 + ar;
      const float bb = bv[cc];
      ushort4 v;
      v.x = f2bf(acc[nt][0] + bb); v.y = f2bf(acc[nt][1] + bb);
      v.z = f2bf(acc[nt][2] + bb); v.w = f2bf(acc[nt][3] + bb);
      *(ushort4*)&VnT[((size_t)b2 * FD + cc) * NN + j0] = v;
    }
  }
}

// ---------------- Kernel 2: full attention + output, MFMA core, QI=2
__global__ __launch_bounds__(512, 2) void k_attn12(
    const float* __restrict__ rel,
    const float* __restrict__ Wk,
    const float* __restrict__ Wv,
    const float* __restrict__ nf,
    const float* __restrict__ bo,
    float* __restrict__ out,
    float* __restrict__ ws) {
  const unsigned short* QbG = (const unsigned short*)(ws + OFF_QB);
  const unsigned short* KnG = (const unsigned short*)(ws + OFF_KNA);
  const unsigned short* VTG = (const unsigned short*)(ws + OFF_VNT);
  const unsigned short* WoT = (const unsigned short*)(ws + OFF_WT) + 3 * FD * FD;

  // XCD-chunked swizzle over 512 blocks (bijective)
  const int bid = (blockIdx.x & 7) * 64 + (blockIdx.x >> 3);
  const int b  = bid >> 7;
  const int i0 = (bid & 127) * QI;
  const int tid = threadIdx.x;
  const int l = tid & 63, w = tid >> 6;
  const int l15 = l & 15, kg = l >> 4;

  __shared__ unsigned short Qb_l[QI * 264];          // 1.0 KB
  __shared__ unsigned short relT[QI * 16 * 264];     // 16.5 KB  [(i*16+r)][j]
  __shared__ unsigned short srelP2[16 * 264];        // 8.25 KB  srel then P2
  __shared__ float qr_l[QI * 8 * 16];                // 1 KB
  __shared__ float ar_l[QI * 8 * 16];                // 1 KB
  __shared__ unsigned short wv_l[QI * 264];          // 1.0 KB

  // ---- stage Qb (threads 0..255: one uint = 2 bf16) + relT (1 (i,j) pair/thread)
  if (tid < 256) {
    const int row = tid >> 7, col2 = tid & 127;
    *(unsigned int*)&Qb_l[row * 264 + col2 * 2] =
        *(const unsigned int*)(QbG + ((size_t)(b * NN + i0 + row)) * FD + col2 * 2);
  }
  {
    const int i = tid >> 8, j = tid & 255;
    const float4* rp = (const float4*)(rel + (((size_t)(b * NN + i0 + i)) * NN + j) * RL);
    #pragma unroll
    for (int q4 = 0; q4 < 4; ++q4) {
      float4 v = rp[q4];
      relT[(i * 16 + q4 * 4 + 0) * 264 + j] = f2bf(v.x);
      relT[(i * 16 + q4 * 4 + 1) * 264 + j] = f2bf(v.y);
      relT[(i * 16 + q4 * 4 + 2) * 264 + j] = f2bf(v.z);
      relT[(i * 16 + q4 * 4 + 3) * 264 + j] = f2bf(v.w);
    }
  }
  __syncthreads();

  // ---- qr[i][h][r] = Qb[i][h*32..] . Wk[256+r][h*32..]  (threads 0..255)
  if (tid < 256) {
    const int i = tid >> 7, h = (tid >> 4) & 7, r = tid & 15;
    const unsigned int* qp = (const unsigned int*)&Qb_l[i * 264 + h * 32];
    const float* wrow = Wk + (FD + r) * FD + h * HD;
    float s = 0.f;
    #pragma unroll
    for (int d2 = 0; d2 < 16; ++d2) {
      unsigned int u = qp[d2];
      s += bf2f((unsigned short)(u & 0xffffu)) * wrow[2 * d2];
      s += bf2f((unsigned short)(u >> 16)) * wrow[2 * d2 + 1];
    }
    qr_l[(i * 8 + h) * 16 + r] = s;
  }
  __syncthreads();

  // ---- phase R: srel[i][h][j] = sum_r qr[i][h][r] * relT[i][r][j]
  // wave w: i = w&1, j-chunk = w>>1 (4 chunks x 64)
  {
    const int i = w & 1;
    const int j0 = (w >> 1) * 64 + l;
    float rv[16];
    #pragma unroll
    for (int r = 0; r < 16; ++r) rv[r] = bf2f(relT[(i * 16 + r) * 264 + j0]);
    #pragma unroll
    for (int h = 0; h < 8; ++h) {
      const float* qv = &qr_l[(i * 8 + h) * 16];
      float s = 0.f;
      #pragma unroll
      for (int r = 0; r < 16; ++r) s += qv[r] * rv[r];
      srelP2[(i * 8 + h) * 264 + j0] = f2bf(s);
    }
  }
  __syncthreads();

  // ---- QK^T MFMA (wave = head) + srel add + softmax in registers
  const int h = w;
  f32x4 acc[16];
  {
    bf16x8 afrag = *(const bf16x8*)&Qb_l[(l15 & 1) * 264 + h * 32 + kg * 8];
    #pragma unroll
    for (int nt = 0; nt < 16; ++nt) {
      bf16x8 bfrag = *(const bf16x8*)(KnG + ((size_t)(b * NN + nt * 16 + l15)) * FD
                                      + h * 32 + kg * 8);
      acc[nt] = __builtin_amdgcn_mfma_f32_16x16x32_bf16(
          afrag, bfrag, (f32x4){0.f, 0.f, 0.f, 0.f}, 0, 0, 0);
    }
    #pragma unroll
    for (int nt = 0; nt < 16; ++nt) {
      #pragma unroll
      for (int ireg = 0; ireg < 4; ++ireg) {
        const int iC = (kg * 4 + ireg) & 1;
        acc[nt][ireg] += bf2f(srelP2[(iC * 8 + h) * 264 + nt * 16 + l15]);
      }
    }
  }
  #pragma unroll
  for (int ireg = 0; ireg < 4; ++ireg) {
    float mx = acc[0][ireg];
    #pragma unroll
    for (int nt = 1; nt < 16; ++nt) mx = fmaxf(mx, acc[nt][ireg]);
    mx = fmaxf(mx, __shfl_xor(mx, 1)); mx = fmaxf(mx, __shfl_xor(mx, 2));
    mx = fmaxf(mx, __shfl_xor(mx, 4)); mx = fmaxf(mx, __shfl_xor(mx, 8));
    float sum = 0.f;
    #pragma unroll
    for (int nt = 0; nt < 16; ++nt) {
      float e = __expf(acc[nt][ireg] - mx);
      acc[nt][ireg] = e; sum += e;
    }
    sum += __shfl_xor(sum, 1); sum += __shfl_xor(sum, 2);
    sum += __shfl_xor(sum, 4); sum += __shfl_xor(sum, 8);
    const float rec = 1.f / sum;
    #pragma unroll
    for (int nt = 0; nt < 16; ++nt) acc[nt][ireg] *= rec;
  }
  __syncthreads();   // srel reads done; srelP2 becomes P2[h][i][j] (stride 528)

  // ---- P2 store: valid C rows = kg==0 lanes, ireg<2 (i = row&1)
  if (l < 16) {
    #pragma unroll
    for (int nt = 0; nt < 16; ++nt)
      #pragma unroll
      for (int ireg = 0; ireg < 2; ++ireg)
        srelP2[h * 528 + ireg * 264 + nt * 16 + l] = f2bf(acc[nt][ireg]);
  }
  __syncthreads();

  // ---- arel MFMA: ar[i](r,h') = relT[i](r,:) @ P2[h'][i](:) ; waves 0..1, i=w
  if (w < 2) {
    const int i = w;
    const int colh = l15 & 7;
    f32x4 aa = (f32x4){0.f, 0.f, 0.f, 0.f};
    #pragma unroll
    for (int ks = 0; ks < 8; ++ks) {
      bf16x8 a = *(const bf16x8*)&relT[(i * 16 + l15) * 264 + ks * 32 + kg * 8];
      bf16x8 bb = *(const bf16x8*)&srelP2[colh * 528 + i * 264 + ks * 32 + kg * 8];
      aa = __builtin_amdgcn_mfma_f32_16x16x32_bf16(a, bb, aa, 0, 0, 0);
    }
    if (l15 < 8) {
      #pragma unroll
      for (int ireg = 0; ireg < 4; ++ireg)
        ar_l[(i * 8 + l15) * 16 + kg * 4 + ireg] = aa[ireg];
    }
  }
  __syncthreads();

  // ---- wv_rel: wv[i][c] = sum_r ar[i][h(c)][r] * Wv[256+r][c]
  {
    const int c = tid & 255, i = tid >> 8, hc = c >> 5;
    const float* ap = &ar_l[(i * 8 + hc) * 16];
    float s = 0.f;
    #pragma unroll
    for (int r = 0; r < 16; ++r) s += ap[r] * Wv[(FD + r) * FD + c];
    wv_l[i * 264 + c] = f2bf(s);
  }
  __syncthreads();

  // ---- PV MFMA (swapped): O^T(d,i) = VnT(d,:) @ P2[h](:,i), wave = head
  {
    const int coli = l15 & 1;
    f32x4 o0 = (f32x4){0.f, 0.f, 0.f, 0.f};
    f32x4 o1 = (f32x4){0.f, 0.f, 0.f, 0.f};
    #pragma unroll
    for (int ks = 0; ks < 8; ++ks) {
      bf16x8 bb = *(const bf16x8*)&srelP2[h * 528 + coli * 264 + ks * 32 + kg * 8];
      bf16x8 a0 = *(const bf16x8*)(VTG + ((size_t)(b * FD + h * 32 + l15)) * NN
                                   + ks * 32 + kg * 8);
      bf16x8 a1 = *(const bf16x8*)(VTG + ((size_t)(b * FD + h * 32 + 16 + l15)) * NN
                                   + ks * 32 + kg * 8);
      o0 = __builtin_amdgcn_mfma_f32_16x16x32_bf16(a0, bb, o0, 0, 0, 0);
      o1 = __builtin_amdgcn_mfma_f32_16x16x32_bf16(a1, bb, o1, 0, 0, 0);
    }
    if (l15 < 2) {
      #pragma unroll
      for (int ireg = 0; ireg < 4; ++ireg) {
        const int c0_ = h * 32 + kg * 4 + ireg;
        const int idx0 = l15 * 264 + c0_;
        const int idx1 = l15 * 264 + c0_ + 16;
        wv_l[idx0] = f2bf(bf2f(wv_l[idx0]) + o0[ireg]);
        wv_l[idx1] = f2bf(bf2f(wv_l[idx1]) + o1[ireg]);
      }
    }
  }
  __syncthreads();

  // ---- out-GEMM MFMA: out[i][cc] = nf + wv @ Wo + bo (wave w: cc in [32w,32w+32))
  {
    const int c0_ = w * 32;
    f32x4 oa0 = (f32x4){0.f, 0.f, 0.f, 0.f};
    f32x4 oa1 = (f32x4){0.f, 0.f, 0.f, 0.f};
    #pragma unroll
    for (int ks = 0; ks < 8; ++ks) {
      bf16x8 a = *(const bf16x8*)&wv_l[(l15 & 1) * 264 + ks * 32 + kg * 8];
      bf16x8 b0 = *(const bf16x8*)(WoT + (c0_ + l15) * FD + ks * 32 + kg * 8);
      bf16x8 b1 = *(const bf16x8*)(WoT + (c0_ + 16 + l15) * FD + ks * 32 + kg * 8);
      oa0 = __builtin_amdgcn_mfma_f32_16x16x32_bf16(a, b0, oa0, 0, 0, 0);
      oa1 = __builtin_amdgcn_mfma_f32_16x16x32_bf16(a, b1, oa1, 0, 0, 0);
    }
    if (l < 16) {
      #pragma unroll
      for (int ireg = 0; ireg < 2; ++ireg) {
        const int row = (b * NN + i0 + ireg) * FD;
        const int cc0 = c0_ + l, cc1 = c0_ + 16 + l;
        out[row + cc0] = nf[row + cc0] + oa0[ireg] + bo[cc0];
        out[row + cc1] = nf[row + cc1] + oa1[ireg] + bo[cc1];
      }
    }
  }
}

extern "C" void kernel_launch(void* const* d_in, const int* in_sizes, int n_in,
                              void* d_out, int out_size, void* d_ws, size_t ws_size,
                              hipStream_t stream) {
  const float* nf  = (const float*)d_in[0];
  const float* rel = (const float*)d_in[1];
  const float* Wq  = (const float*)d_in[2];
  const float* bq  = (const float*)d_in[3];
  const float* Wk  = (const float*)d_in[4];
  const float* bk  = (const float*)d_in[5];
  const float* Wv  = (const float*)d_in[6];
  const float* bv  = (const float*)d_in[7];
  const float* Wo  = (const float*)d_in[8];
  const float* bo  = (const float*)d_in[9];
  float* out = (float*)d_out;
  float* ws  = (float*)d_ws;

  k_prep  <<<dim3(16, 4), 256, 0, stream>>>(Wq, Wk, Wv, Wo, ws);
  k_proj  <<<dim3(16, 12), 256, 0, stream>>>(nf, bq, bk, bv, ws);
  k_attn12<<<BB * NN / QI, 512, 0, stream>>>(rel, Wk, Wv, nf, bo, out, ws);
}

// Round 13
// 38.020 us; speedup vs baseline: 1.2030x; 1.2030x over previous
//
#include <hip/hip_runtime.h>

// GeometricAttention: B=4, N=256, FDIM=256, REL=16, H=8, D=32
//   K[b,i,j] = Kn[b,j] + rel[b,i,j] @ Wk_r          (Kn = nf@Wk_f + bk)
//   scores   = Q.Kn^T + Qr.rel^T                     (Qr = per-head Q @ Wk_r^T)
//   sum_j attn*V = attn@Vn + (attn@rel)@Wv_r         (Vn = nf@Wv_f + bv)
// Round 13: r11 attn core (QI=4, 256 blocks — r12's QI=2 regressed) +
// register prefetch of Kn fragments (kernel start) and VnT fragments (during
// the w<4-only arel phase) to hide L2 latency at 1 block/CU; r12's direct-nf
// k_proj and W-transpose-only k_prep retained.

#define BB 4
#define NN 256
#define FD 256
#define RL 16
#define NH 8
#define HD 32
#define QI 4

typedef __attribute__((ext_vector_type(8))) short bf16x8;
typedef __attribute__((ext_vector_type(4))) float f32x4;

// ws layout (float offsets)
#define OFF_QB   0                          // ushort Qb[b][i][f]  (scaled)
#define OFF_KNA  131072                     // ushort Kn[b][j][f]
#define OFF_VNT  262144                     // ushort VnT[b][f][j]
#define OFF_WT   393216                     // ushort WT[4][c][k]: Wq,Wk_f,Wv_f,Wo

static __device__ __forceinline__ unsigned short f2bf(float x) {
  unsigned int u = __float_as_uint(x);
  unsigned int r = (u + 0x7fffu + ((u >> 16) & 1u)) >> 16;   // RNE
  return (unsigned short)r;
}
static __device__ __forceinline__ float bf2f(unsigned short h) {
  return __uint_as_float(((unsigned int)h) << 16);
}

// ---------------- Kernel 0: W transposes -> WT[c][k] bf16
__global__ __launch_bounds__(256) void k_prep(
    const float* __restrict__ Wq, const float* __restrict__ Wk,
    const float* __restrict__ Wv, const float* __restrict__ Wo,
    float* __restrict__ ws) {
  const int tid = threadIdx.x;
  const int sel = blockIdx.y;          // 0..3: Wq/Wk_f/Wv_f/Wo
  const float* W = (sel == 0) ? Wq : (sel == 1) ? Wk : (sel == 2) ? Wv : Wo;
  unsigned short* WT = (unsigned short*)(ws + OFF_WT) + sel * FD * FD;
  __shared__ unsigned short t[64][72];
  const int tx = blockIdx.x & 3, ty = blockIdx.x >> 2;   // 64x64 tile
  const int cx = tid & 63, r0 = tid >> 6;
  #pragma unroll
  for (int rr = r0; rr < 64; rr += 4)
    t[rr][cx] = f2bf(W[(ty * 64 + rr) * FD + tx * 64 + cx]);
  __syncthreads();
  #pragma unroll
  for (int rr = r0; rr < 64; rr += 4)
    WT[(tx * 64 + rr) * FD + ty * 64 + cx] = t[cx][rr];   // WT[c][k] = W[k][c]
}

// ---------------- Kernel 1: MFMA projections -> Qb / Kn / VnT (all bf16)
__global__ __launch_bounds__(256) void k_proj(
    const float* __restrict__ nf,
    const float* __restrict__ bq, const float* __restrict__ bk,
    const float* __restrict__ bv, float* __restrict__ ws) {
  const int mat = blockIdx.y >> 2;                 // 0=Qb, 1=Kn, 2=VnT
  const int c0 = (blockIdx.y & 3) * 64;
  const int m0 = blockIdx.x * 64 + (threadIdx.x >> 6) * 16;
  const int l = threadIdx.x & 63;
  const unsigned short* WT = (const unsigned short*)(ws + OFF_WT) + mat * FD * FD;
  const int ar = l & 15, kg = l >> 4;
  f32x4 acc[4];
  #pragma unroll
  for (int nt = 0; nt < 4; ++nt) acc[nt] = (f32x4){0.f, 0.f, 0.f, 0.f};
  #pragma unroll
  for (int ks = 0; ks < 8; ++ks) {
    const float* nfp = nf + (m0 + ar) * FD + ks * 32 + kg * 8;
    float4 x0 = *(const float4*)nfp;
    float4 x1 = *(const float4*)(nfp + 4);
    bf16x8 a;
    a[0] = (short)f2bf(x0.x); a[1] = (short)f2bf(x0.y);
    a[2] = (short)f2bf(x0.z); a[3] = (short)f2bf(x0.w);
    a[4] = (short)f2bf(x1.x); a[5] = (short)f2bf(x1.y);
    a[6] = (short)f2bf(x1.z); a[7] = (short)f2bf(x1.w);
    #pragma unroll
    for (int nt = 0; nt < 4; ++nt) {
      bf16x8 b = *(const bf16x8*)(WT + (c0 + nt * 16 + ar) * FD + ks * 32 + kg * 8);
      acc[nt] = __builtin_amdgcn_mfma_f32_16x16x32_bf16(a, b, acc[nt], 0, 0, 0);
    }
  }
  if (mat == 0) {
    const float scale = 0.17677669529663687f;      // 1/sqrt(32)
    unsigned short* Qb = (unsigned short*)(ws + OFF_QB);
    #pragma unroll
    for (int nt = 0; nt < 4; ++nt) {
      const int cc = c0 + nt * 16 + ar;
      const float bb = bq[cc];
      #pragma unroll
      for (int i = 0; i < 4; ++i)
        Qb[(m0 + kg * 4 + i) * FD + cc] = f2bf((acc[nt][i] + bb) * scale);
    }
  } else if (mat == 1) {
    unsigned short* Kn = (unsigned short*)(ws + OFF_KNA);
    #pragma unroll
    for (int nt = 0; nt < 4; ++nt) {
      const int cc = c0 + nt * 16 + ar;
      const float bb = bk[cc];
      #pragma unroll
      for (int i = 0; i < 4; ++i)
        Kn[(m0 + kg * 4 + i) * FD + cc] = f2bf(acc[nt][i] + bb);
    }
  } else {
    unsigned short* VnT = (unsigned short*)(ws + OFF_VNT);
    const int b2 = m0 >> 8, j0 = (m0 & 255) + kg * 4;
    #pragma unroll
    for (int nt = 0; nt < 4; ++nt) {
      const int cc = c0 + nt * 16 + ar;
      const float bb = bv[cc];
      ushort4 v;
      v.x = f2bf(acc[nt][0] + bb); v.y = f2bf(acc[nt][1] + bb);
      v.z = f2bf(acc[nt][2] + bb); v.w = f2bf(acc[nt][3] + bb);
      *(ushort4*)&VnT[((size_t)b2 * FD + cc) * NN + j0] = v;
    }
  }
}

// ---------------- Kernel 2: full attention + output, MFMA core, QI=4
__global__ __launch_bounds__(512, 1) void k_attn13(
    const float* __restrict__ rel,
    const float* __restrict__ Wk,
    const float* __restrict__ Wv,
    const float* __restrict__ nf,
    const float* __restrict__ bo,
    float* __restrict__ out,
    float* __restrict__ ws) {
  const unsigned short* QbG = (const unsigned short*)(ws + OFF_QB);
  const unsigned short* KnG = (const unsigned short*)(ws + OFF_KNA);
  const unsigned short* VTG = (const unsigned short*)(ws + OFF_VNT);
  const unsigned short* WoT = (const unsigned short*)(ws + OFF_WT) + 3 * FD * FD;

  // XCD-chunked swizzle over 256 blocks (bijective)
  const int bid = (blockIdx.x & 7) * 32 + (blockIdx.x >> 3);
  const int b  = bid >> 6;
  const int i0 = (bid & 63) * QI;
  const int tid = threadIdx.x;
  const int l = tid & 63, w = tid >> 6;
  const int l15 = l & 15, kg = l >> 4;
  const int h = w;

  __shared__ unsigned short Qb_l[QI * 264];          // 2.1 KB
  __shared__ unsigned short relT[QI * 16 * 264];     // 33.8 KB [(i*16+r)][j]
  __shared__ unsigned short srelP2[8 * 1064];        // 17.0 KB srel then P2
  __shared__ float qr_l[QI * 8 * 16];                // 2 KB
  __shared__ float ar_l[QI * 8 * 16];                // 2 KB
  __shared__ unsigned short wv_l[QI * 264];          // 2.1 KB

  // ---- PREFETCH: 16 Kn B-fragments for QK^T (global-only dependence;
  // issued here so L2 latency overlaps staging + qr + phase R)
  bf16x8 knpf[16];
  #pragma unroll
  for (int nt = 0; nt < 16; ++nt)
    knpf[nt] = *(const bf16x8*)(KnG + ((size_t)(b * NN + nt * 16 + l15)) * FD
                                + h * 32 + kg * 8);

  // ---- stage Qb (2 bf16 per thread) + relT (transposed bf16)
  {
    const int t2 = tid * 2, row = t2 >> 8, col = t2 & 255;
    *(unsigned int*)&Qb_l[row * 264 + col] =
        *(const unsigned int*)(QbG + ((size_t)(b * NN + i0 + row)) * FD + col);
  }
  #pragma unroll
  for (int m = 0; m < 2; ++m) {
    const int p = tid + 512 * m, i = p >> 8, j = p & 255;
    const float4* rp = (const float4*)(rel + (((size_t)(b * NN + i0 + i)) * NN + j) * RL);
    #pragma unroll
    for (int q4 = 0; q4 < 4; ++q4) {
      float4 v = rp[q4];
      relT[(i * 16 + q4 * 4 + 0) * 264 + j] = f2bf(v.x);
      relT[(i * 16 + q4 * 4 + 1) * 264 + j] = f2bf(v.y);
      relT[(i * 16 + q4 * 4 + 2) * 264 + j] = f2bf(v.z);
      relT[(i * 16 + q4 * 4 + 3) * 264 + j] = f2bf(v.w);
    }
  }
  __syncthreads();

  // ---- qr[i][h][r] = Qb[i][h*32..] . Wk[256+r][h*32..]  (one output/thread)
  {
    const int i = tid >> 7, hq = (tid >> 4) & 7, r = tid & 15;
    const unsigned int* qp = (const unsigned int*)&Qb_l[i * 264 + hq * 32];
    const float* wrow = Wk + (FD + r) * FD + hq * HD;
    float s = 0.f;
    #pragma unroll
    for (int d2 = 0; d2 < 16; ++d2) {
      unsigned int u = qp[d2];
      s += bf2f((unsigned short)(u & 0xffffu)) * wrow[2 * d2];
      s += bf2f((unsigned short)(u >> 16)) * wrow[2 * d2 + 1];
    }
    qr_l[(i * 8 + hq) * 16 + r] = s;
  }
  __syncthreads();

  // ---- phase R: srel[i][h][j] = sum_r qr[i][h][r] * relT[i][r][j]
  {
    const int i = w & 3, jh = w >> 2;
    const int j0 = jh * 128 + l;                  // j0 and j0+64
    float rv0[16], rv1[16];
    #pragma unroll
    for (int r = 0; r < 16; ++r) {
      rv0[r] = bf2f(relT[(i * 16 + r) * 264 + j0]);
      rv1[r] = bf2f(relT[(i * 16 + r) * 264 + j0 + 64]);
    }
    #pragma unroll
    for (int hh = 0; hh < 8; ++hh) {
      const float* qv = &qr_l[(i * 8 + hh) * 16];
      float s0 = 0.f, s1 = 0.f;
      #pragma unroll
      for (int r = 0; r < 16; ++r) { s0 += qv[r] * rv0[r]; s1 += qv[r] * rv1[r]; }
      srelP2[(i * 8 + hh) * 264 + j0]      = f2bf(s0);
      srelP2[(i * 8 + hh) * 264 + j0 + 64] = f2bf(s1);
    }
  }
  __syncthreads();

  // ---- QK^T MFMA (wave = head, prefetched B) + srel add + softmax
  f32x4 acc[16];
  {
    bf16x8 afrag = *(const bf16x8*)&Qb_l[(l15 & 3) * 264 + h * 32 + kg * 8];
    #pragma unroll
    for (int nt = 0; nt < 16; ++nt) {
      acc[nt] = __builtin_amdgcn_mfma_f32_16x16x32_bf16(
          afrag, knpf[nt], (f32x4){0.f, 0.f, 0.f, 0.f}, 0, 0, 0);
    }
    #pragma unroll
    for (int nt = 0; nt < 16; ++nt) {
      #pragma unroll
      for (int ireg = 0; ireg < 4; ++ireg) {
        const int iC = (kg * 4 + ireg) & 3;       // valid rows: kg==0
        acc[nt][ireg] += bf2f(srelP2[(iC * 8 + h) * 264 + nt * 16 + l15]);
      }
    }
  }
  #pragma unroll
  for (int ireg = 0; ireg < 4; ++ireg) {
    float mx = acc[0][ireg];
    #pragma unroll
    for (int nt = 1; nt < 16; ++nt) mx = fmaxf(mx, acc[nt][ireg]);
    mx = fmaxf(mx, __shfl_xor(mx, 1)); mx = fmaxf(mx, __shfl_xor(mx, 2));
    mx = fmaxf(mx, __shfl_xor(mx, 4)); mx = fmaxf(mx, __shfl_xor(mx, 8));
    float sum = 0.f;
    #pragma unroll
    for (int nt = 0; nt < 16; ++nt) {
      float e = __expf(acc[nt][ireg] - mx);
      acc[nt][ireg] = e; sum += e;
    }
    sum += __shfl_xor(sum, 1); sum += __shfl_xor(sum, 2);
    sum += __shfl_xor(sum, 4); sum += __shfl_xor(sum, 8);
    const float rec = 1.f / sum;
    #pragma unroll
    for (int nt = 0; nt < 16; ++nt) acc[nt][ireg] *= rec;
  }
  __syncthreads();   // all srel reads done; srelP2 becomes P2

  // ---- P2[h][i][j] stores (valid rows = kg==0 -> lanes 0..15)
  if (l < 16) {
    #pragma unroll
    for (int nt = 0; nt < 16; ++nt)
      #pragma unroll
      for (int ireg = 0; ireg < 4; ++ireg)
        srelP2[h * 1064 + ireg * 264 + nt * 16 + l] = f2bf(acc[nt][ireg]);
  }

  // ---- PREFETCH: 16 VnT A-fragments for PV (fills waves 4-7's idle arel phase)
  bf16x8 vpf0[8], vpf1[8];
  #pragma unroll
  for (int ks = 0; ks < 8; ++ks) {
    vpf0[ks] = *(const bf16x8*)(VTG + ((size_t)(b * FD + h * 32 + l15)) * NN
                                + ks * 32 + kg * 8);
    vpf1[ks] = *(const bf16x8*)(VTG + ((size_t)(b * FD + h * 32 + 16 + l15)) * NN
                                + ks * 32 + kg * 8);
  }
  __syncthreads();

  // ---- arel MFMA: ar[i](r,h') = relT[i](r,:) @ P2[h'][i](:) (waves 0..3, i=w)
  if (w < 4) {
    const int i = w;
    const int colh = l15 & 7;
    f32x4 aa = (f32x4){0.f, 0.f, 0.f, 0.f};
    #pragma unroll
    for (int ks = 0; ks < 8; ++ks) {
      bf16x8 a = *(const bf16x8*)&relT[(i * 16 + l15) * 264 + ks * 32 + kg * 8];
      bf16x8 bb = *(const bf16x8*)&srelP2[colh * 1064 + i * 264 + ks * 32 + kg * 8];
      aa = __builtin_amdgcn_mfma_f32_16x16x32_bf16(a, bb, aa, 0, 0, 0);
    }
    if (l15 < 8) {
      #pragma unroll
      for (int ireg = 0; ireg < 4; ++ireg)
        ar_l[(i * 8 + l15) * 16 + kg * 4 + ireg] = aa[ireg];
    }
  }
  __syncthreads();

  // ---- wv_rel: wv[i][c] = sum_r ar[i][h(c)][r] * Wv[256+r][c]
  {
    const int c = tid & 255, ii0 = tid >> 8, hc = c >> 5;
    float wvv[16];
    #pragma unroll
    for (int r = 0; r < 16; ++r) wvv[r] = Wv[(FD + r) * FD + c];
    #pragma unroll
    for (int k2 = 0; k2 < 2; ++k2) {
      const int i = ii0 + 2 * k2;
      const float* ap = &ar_l[(i * 8 + hc) * 16];
      float s = 0.f;
      #pragma unroll
      for (int r = 0; r < 16; ++r) s += ap[r] * wvv[r];
      wv_l[i * 264 + c] = f2bf(s);
    }
  }
  __syncthreads();

  // ---- PV MFMA (swapped): O^T(d,i) = VnT(d,:) @ P2[h](:,i), wave = head
  {
    const int coli = l15 & 3;
    f32x4 o0 = (f32x4){0.f, 0.f, 0.f, 0.f};
    f32x4 o1 = (f32x4){0.f, 0.f, 0.f, 0.f};
    #pragma unroll
    for (int ks = 0; ks < 8; ++ks) {
      bf16x8 bb = *(const bf16x8*)&srelP2[h * 1064 + coli * 264 + ks * 32 + kg * 8];
      o0 = __builtin_amdgcn_mfma_f32_16x16x32_bf16(vpf0[ks], bb, o0, 0, 0, 0);
      o1 = __builtin_amdgcn_mfma_f32_16x16x32_bf16(vpf1[ks], bb, o1, 0, 0, 0);
    }
    if (l15 < 4) {
      #pragma unroll
      for (int ireg = 0; ireg < 4; ++ireg) {
        const int c0_ = h * 32 + kg * 4 + ireg;
        const int idx0 = l15 * 264 + c0_;
        const int idx1 = l15 * 264 + c0_ + 16;
        wv_l[idx0] = f2bf(bf2f(wv_l[idx0]) + o0[ireg]);
        wv_l[idx1] = f2bf(bf2f(wv_l[idx1]) + o1[ireg]);
      }
    }
  }
  __syncthreads();

  // ---- out-GEMM MFMA: out[i][cc] = nf + wv @ Wo + bo (wave w: cc in [32w,32w+32))
  {
    const int c0_ = w * 32;
    f32x4 oa0 = (f32x4){0.f, 0.f, 0.f, 0.f};
    f32x4 oa1 = (f32x4){0.f, 0.f, 0.f, 0.f};
    #pragma unroll
    for (int ks = 0; ks < 8; ++ks) {
      bf16x8 a = *(const bf16x8*)&wv_l[(l15 & 3) * 264 + ks * 32 + kg * 8];
      bf16x8 b0 = *(const bf16x8*)(WoT + (c0_ + l15) * FD + ks * 32 + kg * 8);
      bf16x8 b1 = *(const bf16x8*)(WoT + (c0_ + 16 + l15) * FD + ks * 32 + kg * 8);
      oa0 = __builtin_amdgcn_mfma_f32_16x16x32_bf16(a, b0, oa0, 0, 0, 0);
      oa1 = __builtin_amdgcn_mfma_f32_16x16x32_bf16(a, b1, oa1, 0, 0, 0);
    }
    if (l < 16) {
      #pragma unroll
      for (int ireg = 0; ireg < 4; ++ireg) {
        const int row = (b * NN + i0 + ireg) * FD;
        const int cc0 = c0_ + l, cc1 = c0_ + 16 + l;
        out[row + cc0] = nf[row + cc0] + oa0[ireg] + bo[cc0];
        out[row + cc1] = nf[row + cc1] + oa1[ireg] + bo[cc1];
      }
    }
  }
}

extern "C" void kernel_launch(void* const* d_in, const int* in_sizes, int n_in,
                              void* d_out, int out_size, void* d_ws, size_t ws_size,
                              hipStream_t stream) {
  const float* nf  = (const float*)d_in[0];
  const float* rel = (const float*)d_in[1];
  const float* Wq  = (const float*)d_in[2];
  const float* bq  = (const float*)d_in[3];
  const float* Wk  = (const float*)d_in[4];
  const float* bk  = (const float*)d_in[5];
  const float* Wv  = (const float*)d_in[6];
  const float* bv  = (const float*)d_in[7];
  const float* Wo  = (const float*)d_in[8];
  const float* bo  = (const float*)d_in[9];
  float* out = (float*)d_out;
  float* ws  = (float*)d_ws;

  k_prep  <<<dim3(16, 4), 256, 0, stream>>>(Wq, Wk, Wv, Wo, ws);
  k_proj  <<<dim3(16, 12), 256, 0, stream>>>(nf, bq, bk, bv, ws);
  k_attn13<<<BB * NN / QI, 512, 0, stream>>>(rel, Wk, Wv, nf, bo, out, ws);
}